// Round 6
// baseline (721.820 us; speedup 1.0000x reference)
//
#include <hip/hip_runtime.h>

#define EPS_RMS 1.1920929e-7f
#define EPS_SK  1e-6f

typedef __bf16 bf16;
typedef __bf16 bf16x4 __attribute__((ext_vector_type(4)));
typedef __bf16 bf16x8 __attribute__((ext_vector_type(8)));
typedef float  f32x4  __attribute__((ext_vector_type(4)));

typedef __attribute__((address_space(3))) void lds_void;
typedef __attribute__((address_space(1))) void glb_void;

__device__ __forceinline__ void async_copy16(void* lds_dst, const void* gsrc) {
  __builtin_amdgcn_global_load_lds((glb_void*)gsrc, (lds_void*)lds_dst, 16, 0, 0);
}

__device__ __forceinline__ void wait_vmcnt0() {
  asm volatile("s_waitcnt vmcnt(0)" ::: "memory");
}

// bijective XCD-chunk swizzle (m204)
__device__ __forceinline__ void xcd_swizzle(int& bx, int& by) {
  const int gx = gridDim.x, nwg = gx * gridDim.y;
  const int flat = blockIdx.y * gx + blockIdx.x;
  const int q = nwg >> 3, r = nwg & 7;
  const int xcd = flat & 7, i = flat >> 3;
  const int lin = (xcd < r ? xcd * (q + 1) : r * (q + 1) + (xcd - r) * q) + i;
  bx = lin % gx;
  by = lin / gx;
}

// ---------------- K0a: convert w1, w2 to bf16 ----------------
__global__ __launch_bounds__(256) void convert_w_kernel(
    const float* __restrict__ w1, const float* __restrict__ w2,
    bf16* __restrict__ w1b, bf16* __restrict__ w2b) {
  size_t i = ((size_t)blockIdx.x * 256 + threadIdx.x) * 4;
  f32x4 a = *(const f32x4*)(w1 + i);
  f32x4 b = *(const f32x4*)(w2 + i);
  bf16x4 ab, bb;
#pragma unroll
  for (int q = 0; q < 4; ++q) { ab[q] = (bf16)a[q]; bb[q] = (bf16)b[q]; }
  *(bf16x4*)(w1b + i) = ab;
  *(bf16x4*)(w2b + i) = bb;
}

// ---------------- K0b: wnb[32][3072] bf16 = cat(w_pre,w_post,w_res,0)*norm_w ----------------
__global__ __launch_bounds__(256) void prep_wnb_kernel(
    const float* __restrict__ w_pre, const float* __restrict__ w_post,
    const float* __restrict__ w_res, const float* __restrict__ norm_w,
    bf16* __restrict__ wnb) {
  const int i = (blockIdx.x * 256 + threadIdx.x) * 4;   // 98304 total elems
  const int j = i / 3072, k = i - j * 3072;
  f32x4 wv;
  if (j < 24) {
    const float* src = j < 4 ? (w_pre + j * 3072)
                     : (j < 8 ? (w_post + (j - 4) * 3072) : (w_res + (j - 8) * 3072));
    const f32x4 nv = *(const f32x4*)(norm_w + k);
    wv = *(const f32x4*)(src + k);
    wv = wv * nv;
  } else {
    wv = f32x4{0.f, 0.f, 0.f, 0.f};
  }
  bf16x4 o;
#pragma unroll
  for (int q = 0; q < 4; ++q) o[q] = (bf16)wv[q];
  *(bf16x4*)(wnb + i) = o;
}

// ---------------- K1: gate logits via MFMA + fused stream-mix ----------------
__global__ __launch_bounds__(256) void gates_kernel(
    const float* __restrict__ x, const bf16* __restrict__ wnb,
    const float* __restrict__ b_pre, const float* __restrict__ b_post,
    const float* __restrict__ b_res,
    const float* __restrict__ alpha_pre, const float* __restrict__ alpha_post,
    const float* __restrict__ alpha_res, float* __restrict__ gates,
    bf16* __restrict__ xs, bf16* __restrict__ resb) {
  const int t = threadIdx.x, wv = t >> 6, l = t & 63;
  const int r0 = blockIdx.x * 16;
  __shared__ float buf[4][16][32];
  __shared__ float bsq[4][16];
  __shared__ float gm[16][20];   // [batch][0..15]=M, [16..19]=H_pre

  f32x4 acc[2] = {};
  float sq = 0.f;
  const int kbase = wv * 768;
  const size_t arow = (size_t)(r0 + (l & 15)) * 3072;
  const int koff = (l >> 4) * 8;
#pragma unroll 1
  for (int ks = 0; ks < 24; ++ks) {
    const int k0 = kbase + ks * 32 + koff;
    const f32x4 a0 = *(const f32x4*)(x + arow + k0);
    const f32x4 a1 = *(const f32x4*)(x + arow + k0 + 4);
    sq += a0[0]*a0[0] + a0[1]*a0[1] + a0[2]*a0[2] + a0[3]*a0[3]
        + a1[0]*a1[0] + a1[1]*a1[1] + a1[2]*a1[2] + a1[3]*a1[3];
    bf16x8 af;
#pragma unroll
    for (int e = 0; e < 4; ++e) { af[e] = (bf16)a0[e]; af[4 + e] = (bf16)a1[e]; }
#pragma unroll
    for (int nf = 0; nf < 2; ++nf) {
      const bf16x8 bn = *(const bf16x8*)(wnb + (size_t)(nf * 16 + (l & 15)) * 3072 + k0);
      acc[nf] = __builtin_amdgcn_mfma_f32_16x16x32_bf16(af, bn, acc[nf], 0, 0, 0);
    }
  }
  sq += __shfl_xor(sq, 16);
  sq += __shfl_xor(sq, 32);
#pragma unroll
  for (int nf = 0; nf < 2; ++nf)
#pragma unroll
    for (int j = 0; j < 4; ++j)
      buf[wv][(l >> 4) * 4 + j][nf * 16 + (l & 15)] = acc[nf][j];
  if (l < 16) bsq[wv][l] = sq;
  __syncthreads();

  if (t < 16) {
    const int r = t;
    float dv[24];
#pragma unroll
    for (int j = 0; j < 24; ++j)
      dv[j] = buf[0][r][j] + buf[1][r][j] + buf[2][r][j] + buf[3][r][j];
    const float ssq = bsq[0][r] + bsq[1][r] + bsq[2][r] + bsq[3][r];
    const float rms = rsqrtf(ssq * (1.f / 3072.f) + EPS_RMS);
    const float ap = alpha_pre[0], apo = alpha_post[0], ar = alpha_res[0];
    float* g = gates + (size_t)(r0 + r) * 24;
    float M[16];
    float hp[4];
#pragma unroll
    for (int j = 0; j < 4; ++j) {
      const float p = ap * rms * dv[j] + b_pre[j];
      hp[j] = 1.f / (1.f + __expf(-p));
      g[j] = hp[j];
      const float q = apo * rms * dv[4 + j] + b_post[j];
      g[4 + j] = 2.f / (1.f + __expf(-q));
    }
#pragma unroll
    for (int j = 0; j < 16; ++j) M[j] = __expf(ar * rms * dv[8 + j] + b_res[j]);
    for (int it = 0; it < 20; ++it) {
#pragma unroll
      for (int i = 0; i < 4; ++i) {
        const float s = M[i * 4] + M[i * 4 + 1] + M[i * 4 + 2] + M[i * 4 + 3] + EPS_SK;
        const float ri = __fdividef(1.f, s);
#pragma unroll
        for (int j = 0; j < 4; ++j) M[i * 4 + j] *= ri;
      }
#pragma unroll
      for (int j = 0; j < 4; ++j) {
        const float s = M[j] + M[4 + j] + M[8 + j] + M[12 + j] + EPS_SK;
        const float ri = __fdividef(1.f, s);
#pragma unroll
        for (int i = 0; i < 4; ++i) M[i * 4 + j] *= ri;
      }
    }
#pragma unroll
    for (int j = 0; j < 16; ++j) { g[8 + j] = M[j]; gm[r][j] = M[j]; }
#pragma unroll
    for (int j = 0; j < 4; ++j) gm[r][16 + j] = hp[j];
  }
  __syncthreads();

  // ---- fused mix: 16 threads per batch, 12 f32x4 column-chunks each ----
  const int bb = t >> 4, tt = t & 15;
  float mr[4][4], mp[4][4];
#pragma unroll
  for (int i = 0; i < 4; ++i)
#pragma unroll
    for (int j = 0; j < 4; ++j) {
      mr[i][j] = gm[bb][i * 4 + j];
      mp[i][j] = mr[i][j] * gm[bb][16 + j];
    }
  const size_t xb = (size_t)(r0 + bb) * 3072;
#pragma unroll 1
  for (int cc = 0; cc < 12; ++cc) {
    const int c4 = (tt + cc * 16) * 4;
    f32x4 xj[4];
#pragma unroll
    for (int j = 0; j < 4; ++j)
      xj[j] = *(const f32x4*)(x + xb + (size_t)j * 768 + c4);
#pragma unroll
    for (int i = 0; i < 4; ++i) {
      f32x4 vr = mr[i][0] * xj[0] + mr[i][1] * xj[1] + mr[i][2] * xj[2] + mr[i][3] * xj[3];
      f32x4 vs = mp[i][0] * xj[0] + mp[i][1] * xj[1] + mp[i][2] * xj[2] + mp[i][3] * xj[3];
      bf16x4 ro, so;
#pragma unroll
      for (int q = 0; q < 4; ++q) { ro[q] = (bf16)vr[q]; so[q] = (bf16)vs[q]; }
      *(bf16x4*)(resb + xb + (size_t)i * 768 + c4) = ro;
      *(bf16x4*)(xs   + xb + (size_t)i * 768 + c4) = so;
    }
  }
}

// =============== m97-style 128x128 4-wave GEMM core (single buffer, 5 blocks/CU) ===============
// Per K-step: stage A+B (8 x global_load_lds/thread), vmcnt(0), barrier, frag reads +
// 32 MFMA/wave (compiler-scheduled lgkm), barrier. Overlap comes from co-resident
// blocks per CU (m114 implicit wave-level co-schedule). R5 proved 3 blocks >> 1-block
// deep pipeline; R6 pushes to 5 (LDS 5x32KB = 160KB exactly, VGPR 60-64 <= 96 cap).
__device__ __forceinline__ void stage_block(
    const bf16* __restrict__ src, const int rowBase, const int K, const int k0,
    char* ldsBuf, const int blk, const int t) {
  const int r = t >> 3;                 // 0..63 within the 64x64 block
  const int c = (t & 7) ^ (r & 7);      // inverse-swizzled source column granule
  async_copy16(ldsBuf + blk * 8192 + t * 16,
               src + (size_t)(rowBase + blk * 64 + r) * K + k0 + c * 8);
}

__device__ __forceinline__ void gemm128_core(
    const bf16* __restrict__ A, const bf16* __restrict__ B, const int K,
    const int tM, const int tN, char* AL, char* BL, f32x4 (&acc)[4][4]) {
  const int t = threadIdx.x, l = t & 63, w = t >> 6;
  const int wr = w >> 1, wc = w & 1;
  const int NT = K >> 6;
  const int arow = wr * 64 + (l & 15);
  const int brow = wc * 64 + (l & 15);
  const int cb = l >> 4;

  auto frag = [&](const char* base, int row, int ks) -> bf16x8 {
    const int c = ks * 4 + cb;
    return *(const bf16x8*)(base + row * 128 + ((c ^ (row & 7)) << 4));
  };

#pragma unroll 1
  for (int T = 0; T < NT; ++T) {
    const int k0 = T << 6;
#pragma unroll
    for (int b = 0; b < 2; ++b) {
      stage_block(A, tM, K, k0, AL, b, t);
      stage_block(A, tM, K, k0, AL, b, t + 256);
      stage_block(B, tN, K, k0, BL, b, t);
      stage_block(B, tN, K, k0, BL, b, t + 256);
    }
    wait_vmcnt0();
    __builtin_amdgcn_s_barrier();
#pragma unroll
    for (int ks = 0; ks < 2; ++ks) {
      bf16x8 af[4], bv[4];
#pragma unroll
      for (int mi = 0; mi < 4; ++mi) af[mi] = frag(AL, arow + mi * 16, ks);
#pragma unroll
      for (int ni = 0; ni < 4; ++ni) bv[ni] = frag(BL, brow + ni * 16, ks);
#pragma unroll
      for (int mi = 0; mi < 4; ++mi)
#pragma unroll
        for (int ni = 0; ni < 4; ++ni)
          acc[mi][ni] = __builtin_amdgcn_mfma_f32_16x16x32_bf16(af[mi], bv[ni], acc[mi][ni], 0, 0, 0);
    }
    __builtin_amdgcn_s_barrier();
  }
}

// ---------------- K3: h = gelu(xs @ w1^T + b1). BM=128, BN=128 ----------------
__global__ __launch_bounds__(256, 5) void ffn1_kernel(
    const bf16* __restrict__ xs, const bf16* __restrict__ w1b,
    const float* __restrict__ b1, bf16* __restrict__ h) {
  __shared__ __align__(16) char LDS[32768];
  int bx, by; xcd_swizzle(bx, by);
  const int tM = by * 128, tN = bx * 128;
  f32x4 acc[4][4] = {};
  gemm128_core(xs, w1b, 768, tM, tN, LDS, LDS + 16384, acc);

  const int t = threadIdx.x, l = t & 63;
  const int w = t >> 6, wr = w >> 1, wc = w & 1;
  float bias[4];
#pragma unroll
  for (int ni = 0; ni < 4; ++ni) bias[ni] = b1[tN + wc * 64 + ni * 16 + (l & 15)];

  __syncthreads();                        // K-loop done; LDS reusable
  float* wlds = (float*)(LDS + w * 8192); // per-wave 16 rows x 64 cols f32, stride 68
#pragma unroll
  for (int mi = 0; mi < 4; ++mi) {
#pragma unroll
    for (int j = 0; j < 4; ++j) {
      const int r = (l >> 4) * 4 + j;
#pragma unroll
      for (int ni = 0; ni < 4; ++ni) {
        const float v = acc[mi][ni][j] + bias[ni];
        const float y2 = 1.5957691216f * (v + 0.044715f * v * v * v);
        wlds[r * 68 + ni * 16 + (l & 15)] = __fdividef(v, 1.f + __expf(-y2));
      }
    }
    const int rr = l >> 3, c0 = (l & 7) * 8;
#pragma unroll
    for (int half = 0; half < 2; ++half) {
      const int row = rr + half * 8;
      const f32x4 u0 = *(const f32x4*)(wlds + row * 68 + c0);
      const f32x4 u1 = *(const f32x4*)(wlds + row * 68 + c0 + 4);
      bf16x8 ov;
#pragma unroll
      for (int q = 0; q < 4; ++q) { ov[q] = (bf16)u0[q]; ov[4 + q] = (bf16)u1[q]; }
      *(bf16x8*)(h + (size_t)(tM + wr * 64 + mi * 16 + row) * 3072 + tN + wc * 64 + c0) = ov;
    }
  }
}

// ---------------- K4: out = res_bf16 + (h @ w2^T + b2) * H_post. BM=128, BN=128 ----------------
__global__ __launch_bounds__(256, 5) void ffn2_kernel(
    const bf16* __restrict__ h, const bf16* __restrict__ w2b,
    const float* __restrict__ b2, const float* __restrict__ gates,
    const bf16* __restrict__ resb, float* __restrict__ outp, const int m0) {
  __shared__ __align__(16) char LDS[32768];
  int bx, by; xcd_swizzle(bx, by);
  const int tM = by * 128, tN = bx * 128;
  f32x4 acc[4][4] = {};
  gemm128_core(h, w2b, 3072, tM, tN, LDS, LDS + 16384, acc);

  const int t = threadIdx.x, l = t & 63;
  const int w = t >> 6, wr = w >> 1, wc = w & 1;
  float bias[4];
#pragma unroll
  for (int ni = 0; ni < 4; ++ni) bias[ni] = b2[tN + wc * 64 + ni * 16 + (l & 15)];

  __syncthreads();                        // K-loop done; LDS reusable
  float* wlds = (float*)(LDS + w * 8192); // per-wave 16 rows x 64 cols f32, stride 68
#pragma unroll
  for (int mi = 0; mi < 4; ++mi) {
#pragma unroll
    for (int j = 0; j < 4; ++j) {
      const int r = (l >> 4) * 4 + j;
#pragma unroll
      for (int ni = 0; ni < 4; ++ni)
        wlds[r * 68 + ni * 16 + (l & 15)] = acc[mi][ni][j] + bias[ni];
    }
#pragma unroll
    for (int rep = 0; rep < 4; ++rep) {
      const int row = rep * 4 + (l >> 4);   // 0..15
      const int cs = l & 15;                // f32x4 chunk within 64 cols
      const int mG = m0 + tM + wr * 64 + mi * 16 + row;
      const float hp = gates[(size_t)(mG >> 2) * 24 + 4 + (mG & 3)];
      const f32x4 v = *(const f32x4*)(wlds + row * 68 + cs * 4);
      const bf16x4 rb = *(const bf16x4*)(resb + (size_t)mG * 768 + tN + wc * 64 + cs * 4);
      f32x4 o;
#pragma unroll
      for (int q = 0; q < 4; ++q) o[q] = (float)rb[q] + v[q] * hp;
      *(f32x4*)(outp + (size_t)mG * 768 + tN + wc * 64 + cs * 4) = o;
    }
  }
}

// ---------------- launcher ----------------
extern "C" void kernel_launch(void* const* d_in, const int* in_sizes, int n_in,
                              void* d_out, int out_size, void* d_ws, size_t ws_size,
                              hipStream_t stream) {
  (void)in_sizes; (void)n_in; (void)out_size;
  const float* x         = (const float*)d_in[0];
  const float* norm_w    = (const float*)d_in[1];
  const float* w_pre     = (const float*)d_in[2];
  const float* b_pre     = (const float*)d_in[3];
  const float* w_post    = (const float*)d_in[4];
  const float* b_post    = (const float*)d_in[5];
  const float* w_res     = (const float*)d_in[6];
  const float* b_res     = (const float*)d_in[7];
  const float* alpha_pre = (const float*)d_in[8];
  const float* alpha_post= (const float*)d_in[9];
  const float* alpha_res = (const float*)d_in[10];
  const float* w1        = (const float*)d_in[11];
  const float* b1        = (const float*)d_in[12];
  const float* w2        = (const float*)d_in[13];
  const float* b2        = (const float*)d_in[14];
  float* outp = (float*)d_out;

  char* ws = (char*)d_ws;
  float* gates = (float*)ws;                        //   786432 B
  bf16*  w1b   = (bf16*)(ws + 786432);              //  4718592 B
  bf16*  w2b   = (bf16*)(ws + 5505024);             //  4718592 B
  bf16*  xs    = (bf16*)(ws + 10223616);            // 50331648 B
  bf16*  resb  = (bf16*)(ws + 60555264);            // 50331648 B
  bf16*  wnb   = (bf16*)(ws + 110886912);           //   196608 B
  bf16*  h     = (bf16*)(ws + 111083520);           // chunked

  size_t avail = ws_size > 111083520 ? ws_size - 111083520 : 0;
  long hrows = (long)(avail / (3072 * 2));
  hrows = (hrows / 256) * 256;
  if (hrows > 32768) hrows = 32768;
  if (hrows < 256) hrows = 256;

  convert_w_kernel<<<dim3(2304), dim3(256), 0, stream>>>(w1, w2, w1b, w2b);
  prep_wnb_kernel<<<dim3(96), dim3(256), 0, stream>>>(w_pre, w_post, w_res, norm_w, wnb);
  gates_kernel<<<dim3(512), dim3(256), 0, stream>>>(
      x, wnb, b_pre, b_post, b_res, alpha_pre, alpha_post, alpha_res, gates, xs, resb);

  for (long mo = 0; mo < 32768; mo += hrows) {
    const long mm = (32768 - mo) < hrows ? (32768 - mo) : hrows;
    ffn1_kernel<<<dim3(24, (unsigned)(mm / 128)), dim3(256), 0, stream>>>(
        xs + mo * 768, w1b, b1, h);
    ffn2_kernel<<<dim3(6, (unsigned)(mm / 128)), dim3(256), 0, stream>>>(
        h, w2b, b2, gates, resb, outp, (int)mo);
  }
}

// Round 7
// 484.857 us; speedup vs baseline: 1.4887x; 1.4887x over previous
//
#include <hip/hip_runtime.h>

#define EPS_RMS 1.1920929e-7f
#define EPS_SK  1e-6f

typedef __bf16 bf16;
typedef __bf16 bf16x4 __attribute__((ext_vector_type(4)));
typedef __bf16 bf16x8 __attribute__((ext_vector_type(8)));
typedef float  f32x4  __attribute__((ext_vector_type(4)));
typedef float  f32x16 __attribute__((ext_vector_type(16)));

typedef __attribute__((address_space(3))) void lds_void;
typedef __attribute__((address_space(1))) void glb_void;

__device__ __forceinline__ void async_copy16(void* lds_dst, const void* gsrc) {
  __builtin_amdgcn_global_load_lds((glb_void*)gsrc, (lds_void*)lds_dst, 16, 0, 0);
}

__device__ __forceinline__ void wait_vmcnt0() {
  asm volatile("s_waitcnt vmcnt(0)" ::: "memory");
}

// bijective XCD-chunk swizzle (m204)
__device__ __forceinline__ void xcd_swizzle(int& bx, int& by) {
  const int gx = gridDim.x, nwg = gx * gridDim.y;
  const int flat = blockIdx.y * gx + blockIdx.x;
  const int q = nwg >> 3, r = nwg & 7;
  const int xcd = flat & 7, i = flat >> 3;
  const int lin = (xcd < r ? xcd * (q + 1) : r * (q + 1) + (xcd - r) * q) + i;
  bx = lin % gx;
  by = lin / gx;
}

// ---------------- K0a: convert w1, w2 to bf16 ----------------
__global__ __launch_bounds__(256) void convert_w_kernel(
    const float* __restrict__ w1, const float* __restrict__ w2,
    bf16* __restrict__ w1b, bf16* __restrict__ w2b) {
  size_t i = ((size_t)blockIdx.x * 256 + threadIdx.x) * 4;
  f32x4 a = *(const f32x4*)(w1 + i);
  f32x4 b = *(const f32x4*)(w2 + i);
  bf16x4 ab, bb;
#pragma unroll
  for (int q = 0; q < 4; ++q) { ab[q] = (bf16)a[q]; bb[q] = (bf16)b[q]; }
  *(bf16x4*)(w1b + i) = ab;
  *(bf16x4*)(w2b + i) = bb;
}

// ---------------- K0b: wnb[32][3072] bf16 = cat(w_pre,w_post,w_res,0)*norm_w ----------------
__global__ __launch_bounds__(256) void prep_wnb_kernel(
    const float* __restrict__ w_pre, const float* __restrict__ w_post,
    const float* __restrict__ w_res, const float* __restrict__ norm_w,
    bf16* __restrict__ wnb) {
  const int i = (blockIdx.x * 256 + threadIdx.x) * 4;   // 98304 total elems
  const int j = i / 3072, k = i - j * 3072;
  f32x4 wv;
  if (j < 24) {
    const float* src = j < 4 ? (w_pre + j * 3072)
                     : (j < 8 ? (w_post + (j - 4) * 3072) : (w_res + (j - 8) * 3072));
    const f32x4 nv = *(const f32x4*)(norm_w + k);
    wv = *(const f32x4*)(src + k);
    wv = wv * nv;
  } else {
    wv = f32x4{0.f, 0.f, 0.f, 0.f};
  }
  bf16x4 o;
#pragma unroll
  for (int q = 0; q < 4; ++q) o[q] = (bf16)wv[q];
  *(bf16x4*)(wnb + i) = o;
}

// ---------------- K1: gate logits via MFMA + fused stream-mix ----------------
__global__ __launch_bounds__(256) void gates_kernel(
    const float* __restrict__ x, const bf16* __restrict__ wnb,
    const float* __restrict__ b_pre, const float* __restrict__ b_post,
    const float* __restrict__ b_res,
    const float* __restrict__ alpha_pre, const float* __restrict__ alpha_post,
    const float* __restrict__ alpha_res, float* __restrict__ gates,
    bf16* __restrict__ xs, bf16* __restrict__ resb) {
  const int t = threadIdx.x, wv = t >> 6, l = t & 63;
  const int r0 = blockIdx.x * 16;
  __shared__ float buf[4][16][32];
  __shared__ float bsq[4][16];
  __shared__ float gm[16][20];   // [batch][0..15]=M, [16..19]=H_pre

  f32x4 acc[2] = {};
  float sq = 0.f;
  const int kbase = wv * 768;
  const size_t arow = (size_t)(r0 + (l & 15)) * 3072;
  const int koff = (l >> 4) * 8;
#pragma unroll 1
  for (int ks = 0; ks < 24; ++ks) {
    const int k0 = kbase + ks * 32 + koff;
    const f32x4 a0 = *(const f32x4*)(x + arow + k0);
    const f32x4 a1 = *(const f32x4*)(x + arow + k0 + 4);
    sq += a0[0]*a0[0] + a0[1]*a0[1] + a0[2]*a0[2] + a0[3]*a0[3]
        + a1[0]*a1[0] + a1[1]*a1[1] + a1[2]*a1[2] + a1[3]*a1[3];
    bf16x8 af;
#pragma unroll
    for (int e = 0; e < 4; ++e) { af[e] = (bf16)a0[e]; af[4 + e] = (bf16)a1[e]; }
#pragma unroll
    for (int nf = 0; nf < 2; ++nf) {
      const bf16x8 bn = *(const bf16x8*)(wnb + (size_t)(nf * 16 + (l & 15)) * 3072 + k0);
      acc[nf] = __builtin_amdgcn_mfma_f32_16x16x32_bf16(af, bn, acc[nf], 0, 0, 0);
    }
  }
  sq += __shfl_xor(sq, 16);
  sq += __shfl_xor(sq, 32);
#pragma unroll
  for (int nf = 0; nf < 2; ++nf)
#pragma unroll
    for (int j = 0; j < 4; ++j)
      buf[wv][(l >> 4) * 4 + j][nf * 16 + (l & 15)] = acc[nf][j];
  if (l < 16) bsq[wv][l] = sq;
  __syncthreads();

  if (t < 16) {
    const int r = t;
    float dv[24];
#pragma unroll
    for (int j = 0; j < 24; ++j)
      dv[j] = buf[0][r][j] + buf[1][r][j] + buf[2][r][j] + buf[3][r][j];
    const float ssq = bsq[0][r] + bsq[1][r] + bsq[2][r] + bsq[3][r];
    const float rms = rsqrtf(ssq * (1.f / 3072.f) + EPS_RMS);
    const float ap = alpha_pre[0], apo = alpha_post[0], ar = alpha_res[0];
    float* g = gates + (size_t)(r0 + r) * 24;
    float M[16];
    float hp[4];
#pragma unroll
    for (int j = 0; j < 4; ++j) {
      const float p = ap * rms * dv[j] + b_pre[j];
      hp[j] = 1.f / (1.f + __expf(-p));
      g[j] = hp[j];
      const float q = apo * rms * dv[4 + j] + b_post[j];
      g[4 + j] = 2.f / (1.f + __expf(-q));
    }
#pragma unroll
    for (int j = 0; j < 16; ++j) M[j] = __expf(ar * rms * dv[8 + j] + b_res[j]);
    for (int it = 0; it < 20; ++it) {
#pragma unroll
      for (int i = 0; i < 4; ++i) {
        const float s = M[i * 4] + M[i * 4 + 1] + M[i * 4 + 2] + M[i * 4 + 3] + EPS_SK;
        const float ri = __fdividef(1.f, s);
#pragma unroll
        for (int j = 0; j < 4; ++j) M[i * 4 + j] *= ri;
      }
#pragma unroll
      for (int j = 0; j < 4; ++j) {
        const float s = M[j] + M[4 + j] + M[8 + j] + M[12 + j] + EPS_SK;
        const float ri = __fdividef(1.f, s);
#pragma unroll
        for (int i = 0; i < 4; ++i) M[i * 4 + j] *= ri;
      }
    }
#pragma unroll
    for (int j = 0; j < 16; ++j) { g[8 + j] = M[j]; gm[r][j] = M[j]; }
#pragma unroll
    for (int j = 0; j < 4; ++j) gm[r][16 + j] = hp[j];
  }
  __syncthreads();

  // ---- fused mix: 16 threads per batch, 12 f32x4 column-chunks each ----
  const int bb = t >> 4, tt = t & 15;
  float mr[4][4], mp[4][4];
#pragma unroll
  for (int i = 0; i < 4; ++i)
#pragma unroll
    for (int j = 0; j < 4; ++j) {
      mr[i][j] = gm[bb][i * 4 + j];
      mp[i][j] = mr[i][j] * gm[bb][16 + j];
    }
  const size_t xb = (size_t)(r0 + bb) * 3072;
#pragma unroll 1
  for (int cc = 0; cc < 12; ++cc) {
    const int c4 = (tt + cc * 16) * 4;
    f32x4 xj[4];
#pragma unroll
    for (int j = 0; j < 4; ++j)
      xj[j] = *(const f32x4*)(x + xb + (size_t)j * 768 + c4);
#pragma unroll
    for (int i = 0; i < 4; ++i) {
      f32x4 vr = mr[i][0] * xj[0] + mr[i][1] * xj[1] + mr[i][2] * xj[2] + mr[i][3] * xj[3];
      f32x4 vs = mp[i][0] * xj[0] + mp[i][1] * xj[1] + mp[i][2] * xj[2] + mp[i][3] * xj[3];
      bf16x4 ro, so;
#pragma unroll
      for (int q = 0; q < 4; ++q) { ro[q] = (bf16)vr[q]; so[q] = (bf16)vs[q]; }
      *(bf16x4*)(resb + xb + (size_t)i * 768 + c4) = ro;
      *(bf16x4*)(xs   + xb + (size_t)i * 768 + c4) = so;
    }
  }
}

// =============== m97-style 128x128 4-wave GEMM core, 32x32x16 MFMA ===============
// Same staging/barrier structure as R5 (proven 805 TF, 3-4 blocks/CU); inner op
// switched to mfma_f32_32x32x16_bf16: half the MFMA instructions for the same
// FLOPs (issue-slot relief) + higher pipe rate (2382 vs 2176 TF ubench).
// A-frag: lane holds row (l&31), k = ks*16 + (l>>5)*8 .. +8 (b128 read).
// C/D: col = lane&31, row = (reg&3) + 8*(reg>>2) + 4*(lane>>5)  [m74/m101].
__device__ __forceinline__ void stage_block(
    const bf16* __restrict__ src, const int rowBase, const int K, const int k0,
    char* ldsBuf, const int blk, const int t) {
  const int r = t >> 3;                 // 0..63 within the 64x64 block
  const int c = (t & 7) ^ (r & 7);      // inverse-swizzled source column granule
  async_copy16(ldsBuf + blk * 8192 + t * 16,
               src + (size_t)(rowBase + blk * 64 + r) * K + k0 + c * 8);
}

__device__ __forceinline__ void gemm128_core(
    const bf16* __restrict__ A, const bf16* __restrict__ B, const int K,
    const int tM, const int tN, char* AL, char* BL, f32x16 (&acc)[2][2]) {
  const int t = threadIdx.x, l = t & 63, w = t >> 6;
  const int wr = w >> 1, wc = w & 1;
  const int NT = K >> 6;
  const int arow = wr * 64 + (l & 31);
  const int brow = wc * 64 + (l & 31);
  const int cb = l >> 5;                // k-granule group (0 or 1)

  auto frag = [&](const char* base, int row, int ks) -> bf16x8 {
    const int c = ks * 2 + cb;          // 16B granule 0..7 within the 128B row
    return *(const bf16x8*)(base + row * 128 + ((c ^ (row & 7)) << 4));
  };

#pragma unroll 1
  for (int T = 0; T < NT; ++T) {
    const int k0 = T << 6;
#pragma unroll
    for (int b = 0; b < 2; ++b) {
      stage_block(A, tM, K, k0, AL, b, t);
      stage_block(A, tM, K, k0, AL, b, t + 256);
      stage_block(B, tN, K, k0, BL, b, t);
      stage_block(B, tN, K, k0, BL, b, t + 256);
    }
    wait_vmcnt0();
    __builtin_amdgcn_s_barrier();
#pragma unroll
    for (int ks = 0; ks < 4; ++ks) {
      bf16x8 af0 = frag(AL, arow, ks);
      bf16x8 af1 = frag(AL, arow + 32, ks);
      bf16x8 bv0 = frag(BL, brow, ks);
      bf16x8 bv1 = frag(BL, brow + 32, ks);
      acc[0][0] = __builtin_amdgcn_mfma_f32_32x32x16_bf16(af0, bv0, acc[0][0], 0, 0, 0);
      acc[0][1] = __builtin_amdgcn_mfma_f32_32x32x16_bf16(af0, bv1, acc[0][1], 0, 0, 0);
      acc[1][0] = __builtin_amdgcn_mfma_f32_32x32x16_bf16(af1, bv0, acc[1][0], 0, 0, 0);
      acc[1][1] = __builtin_amdgcn_mfma_f32_32x32x16_bf16(af1, bv1, acc[1][1], 0, 0, 0);
    }
    __builtin_amdgcn_s_barrier();
  }
}

// ---------------- K3: h = gelu(xs @ w1^T + b1). BM=128, BN=128 ----------------
__global__ __launch_bounds__(256, 3) void ffn1_kernel(
    const bf16* __restrict__ xs, const bf16* __restrict__ w1b,
    const float* __restrict__ b1, bf16* __restrict__ h) {
  __shared__ __align__(16) char LDS[32768];
  int bx, by; xcd_swizzle(bx, by);
  const int tM = by * 128, tN = bx * 128;
  f32x16 acc[2][2] = {};
  gemm128_core(xs, w1b, 768, tM, tN, LDS, LDS + 16384, acc);

  const int t = threadIdx.x, l = t & 63;
  const int w = t >> 6, wr = w >> 1, wc = w & 1;
  float bias_n[2];
#pragma unroll
  for (int ni2 = 0; ni2 < 2; ++ni2)
    bias_n[ni2] = b1[tN + wc * 64 + ni2 * 32 + (l & 31)];

  __syncthreads();                        // K-loop done; LDS reusable
  float* wlds = (float*)(LDS + w * 8192); // per-wave 16 rows x 64 cols f32, stride 68
#pragma unroll
  for (int mi2 = 0; mi2 < 2; ++mi2) {
#pragma unroll
    for (int p = 0; p < 2; ++p) {
#pragma unroll
      for (int q = 0; q < 8; ++q) {
        const int rl = (q & 3) + 8 * (q >> 2) + 4 * (l >> 5);   // 0..15
#pragma unroll
        for (int ni2 = 0; ni2 < 2; ++ni2) {
          const float v = acc[mi2][ni2][p * 8 + q] + bias_n[ni2];
          const float y2 = 1.5957691216f * (v + 0.044715f * v * v * v);
          wlds[rl * 68 + ni2 * 32 + (l & 31)] = __fdividef(v, 1.f + __expf(-y2));
        }
      }
      const int rr = l >> 3, c0 = (l & 7) * 8;
#pragma unroll
      for (int half = 0; half < 2; ++half) {
        const int row = rr + half * 8;
        const f32x4 u0 = *(const f32x4*)(wlds + row * 68 + c0);
        const f32x4 u1 = *(const f32x4*)(wlds + row * 68 + c0 + 4);
        bf16x8 ov;
#pragma unroll
        for (int q = 0; q < 4; ++q) { ov[q] = (bf16)u0[q]; ov[4 + q] = (bf16)u1[q]; }
        *(bf16x8*)(h + (size_t)(tM + wr * 64 + mi2 * 32 + p * 16 + row) * 3072
                     + tN + wc * 64 + c0) = ov;
      }
    }
  }
}

// ---------------- K4: out = res_bf16 + (h @ w2^T + b2) * H_post. BM=128, BN=128 ----------------
__global__ __launch_bounds__(256, 3) void ffn2_kernel(
    const bf16* __restrict__ h, const bf16* __restrict__ w2b,
    const float* __restrict__ b2, const float* __restrict__ gates,
    const bf16* __restrict__ resb, float* __restrict__ outp, const int m0) {
  __shared__ __align__(16) char LDS[32768];
  int bx, by; xcd_swizzle(bx, by);
  const int tM = by * 128, tN = bx * 128;
  f32x16 acc[2][2] = {};
  gemm128_core(h, w2b, 3072, tM, tN, LDS, LDS + 16384, acc);

  const int t = threadIdx.x, l = t & 63;
  const int w = t >> 6, wr = w >> 1, wc = w & 1;
  float bias_n[2];
#pragma unroll
  for (int ni2 = 0; ni2 < 2; ++ni2)
    bias_n[ni2] = b2[tN + wc * 64 + ni2 * 32 + (l & 31)];

  __syncthreads();                        // K-loop done; LDS reusable
  float* wlds = (float*)(LDS + w * 8192); // per-wave 16 rows x 64 cols f32, stride 68
#pragma unroll
  for (int mi2 = 0; mi2 < 2; ++mi2) {
#pragma unroll
    for (int p = 0; p < 2; ++p) {
#pragma unroll
      for (int q = 0; q < 8; ++q) {
        const int rl = (q & 3) + 8 * (q >> 2) + 4 * (l >> 5);   // 0..15
#pragma unroll
        for (int ni2 = 0; ni2 < 2; ++ni2)
          wlds[rl * 68 + ni2 * 32 + (l & 31)] = acc[mi2][ni2][p * 8 + q] + bias_n[ni2];
      }
#pragma unroll
      for (int rep = 0; rep < 4; ++rep) {
        const int row = rep * 4 + (l >> 4);   // 0..15
        const int cs = l & 15;                // f32x4 chunk within 64 cols
        const int mG = m0 + tM + wr * 64 + mi2 * 32 + p * 16 + row;
        const float hp = gates[(size_t)(mG >> 2) * 24 + 4 + (mG & 3)];
        const f32x4 v = *(const f32x4*)(wlds + row * 68 + cs * 4);
        const bf16x4 rb = *(const bf16x4*)(resb + (size_t)mG * 768 + tN + wc * 64 + cs * 4);
        f32x4 o;
#pragma unroll
        for (int q = 0; q < 4; ++q) o[q] = (float)rb[q] + v[q] * hp;
        *(f32x4*)(outp + (size_t)mG * 768 + tN + wc * 64 + cs * 4) = o;
      }
    }
  }
}

// ---------------- launcher ----------------
extern "C" void kernel_launch(void* const* d_in, const int* in_sizes, int n_in,
                              void* d_out, int out_size, void* d_ws, size_t ws_size,
                              hipStream_t stream) {
  (void)in_sizes; (void)n_in; (void)out_size;
  const float* x         = (const float*)d_in[0];
  const float* norm_w    = (const float*)d_in[1];
  const float* w_pre     = (const float*)d_in[2];
  const float* b_pre     = (const float*)d_in[3];
  const float* w_post    = (const float*)d_in[4];
  const float* b_post    = (const float*)d_in[5];
  const float* w_res     = (const float*)d_in[6];
  const float* b_res     = (const float*)d_in[7];
  const float* alpha_pre = (const float*)d_in[8];
  const float* alpha_post= (const float*)d_in[9];
  const float* alpha_res = (const float*)d_in[10];
  const float* w1        = (const float*)d_in[11];
  const float* b1        = (const float*)d_in[12];
  const float* w2        = (const float*)d_in[13];
  const float* b2        = (const float*)d_in[14];
  float* outp = (float*)d_out;

  char* ws = (char*)d_ws;
  float* gates = (float*)ws;                        //   786432 B
  bf16*  w1b   = (bf16*)(ws + 786432);              //  4718592 B
  bf16*  w2b   = (bf16*)(ws + 5505024);             //  4718592 B
  bf16*  xs    = (bf16*)(ws + 10223616);            // 50331648 B
  bf16*  resb  = (bf16*)(ws + 60555264);            // 50331648 B
  bf16*  wnb   = (bf16*)(ws + 110886912);           //   196608 B
  bf16*  h     = (bf16*)(ws + 111083520);           // chunked

  size_t avail = ws_size > 111083520 ? ws_size - 111083520 : 0;
  long hrows = (long)(avail / (3072 * 2));
  hrows = (hrows / 256) * 256;
  if (hrows > 32768) hrows = 32768;
  if (hrows < 256) hrows = 256;

  convert_w_kernel<<<dim3(2304), dim3(256), 0, stream>>>(w1, w2, w1b, w2b);
  prep_wnb_kernel<<<dim3(96), dim3(256), 0, stream>>>(w_pre, w_post, w_res, norm_w, wnb);
  gates_kernel<<<dim3(512), dim3(256), 0, stream>>>(
      x, wnb, b_pre, b_post, b_res, alpha_pre, alpha_post, alpha_res, gates, xs, resb);

  for (long mo = 0; mo < 32768; mo += hrows) {
    const long mm = (32768 - mo) < hrows ? (32768 - mo) : hrows;
    ffn1_kernel<<<dim3(24, (unsigned)(mm / 128)), dim3(256), 0, stream>>>(
        xs + mo * 768, w1b, b1, h);
    ffn2_kernel<<<dim3(6, (unsigned)(mm / 128)), dim3(256), 0, stream>>>(
        h, w2b, b2, gates, resb, outp, (int)mo);
  }
}

// Round 8
// 443.700 us; speedup vs baseline: 1.6268x; 1.0928x over previous
//
#include <hip/hip_runtime.h>

#define EPS_RMS 1.1920929e-7f
#define EPS_SK  1e-6f

typedef __bf16 bf16;
typedef __bf16 bf16x4 __attribute__((ext_vector_type(4)));
typedef __bf16 bf16x8 __attribute__((ext_vector_type(8)));
typedef float  f32x4  __attribute__((ext_vector_type(4)));

typedef __attribute__((address_space(3))) void lds_void;
typedef __attribute__((address_space(1))) void glb_void;

__device__ __forceinline__ void async_copy16(void* lds_dst, const void* gsrc) {
  __builtin_amdgcn_global_load_lds((glb_void*)gsrc, (lds_void*)lds_dst, 16, 0, 0);
}

__device__ __forceinline__ void wait_vmcnt0() {
  asm volatile("s_waitcnt vmcnt(0)" ::: "memory");
}

// bijective XCD-chunk swizzle (m204)
__device__ __forceinline__ void xcd_swizzle(int& bx, int& by) {
  const int gx = gridDim.x, nwg = gx * gridDim.y;
  const int flat = blockIdx.y * gx + blockIdx.x;
  const int q = nwg >> 3, r = nwg & 7;
  const int xcd = flat & 7, i = flat >> 3;
  const int lin = (xcd < r ? xcd * (q + 1) : r * (q + 1) + (xcd - r) * q) + i;
  bx = lin % gx;
  by = lin / gx;
}

// ---------------- K0a: convert w1, w2 to bf16 ----------------
__global__ __launch_bounds__(256) void convert_w_kernel(
    const float* __restrict__ w1, const float* __restrict__ w2,
    bf16* __restrict__ w1b, bf16* __restrict__ w2b) {
  size_t i = ((size_t)blockIdx.x * 256 + threadIdx.x) * 4;
  f32x4 a = *(const f32x4*)(w1 + i);
  f32x4 b = *(const f32x4*)(w2 + i);
  bf16x4 ab, bb;
#pragma unroll
  for (int q = 0; q < 4; ++q) { ab[q] = (bf16)a[q]; bb[q] = (bf16)b[q]; }
  *(bf16x4*)(w1b + i) = ab;
  *(bf16x4*)(w2b + i) = bb;
}

// ---------------- K0b: wnb[32][3072] bf16 = cat(w_pre,w_post,w_res,0)*norm_w ----------------
__global__ __launch_bounds__(256) void prep_wnb_kernel(
    const float* __restrict__ w_pre, const float* __restrict__ w_post,
    const float* __restrict__ w_res, const float* __restrict__ norm_w,
    bf16* __restrict__ wnb) {
  const int i = (blockIdx.x * 256 + threadIdx.x) * 4;   // 98304 total elems
  const int j = i / 3072, k = i - j * 3072;
  f32x4 wv;
  if (j < 24) {
    const float* src = j < 4 ? (w_pre + j * 3072)
                     : (j < 8 ? (w_post + (j - 4) * 3072) : (w_res + (j - 8) * 3072));
    const f32x4 nv = *(const f32x4*)(norm_w + k);
    wv = *(const f32x4*)(src + k);
    wv = wv * nv;
  } else {
    wv = f32x4{0.f, 0.f, 0.f, 0.f};
  }
  bf16x4 o;
#pragma unroll
  for (int q = 0; q < 4; ++q) o[q] = (bf16)wv[q];
  *(bf16x4*)(wnb + i) = o;
}

// ---------------- K1: gate logits via MFMA + fused stream-mix ----------------
__global__ __launch_bounds__(256) void gates_kernel(
    const float* __restrict__ x, const bf16* __restrict__ wnb,
    const float* __restrict__ b_pre, const float* __restrict__ b_post,
    const float* __restrict__ b_res,
    const float* __restrict__ alpha_pre, const float* __restrict__ alpha_post,
    const float* __restrict__ alpha_res, float* __restrict__ gates,
    bf16* __restrict__ xs, bf16* __restrict__ resb) {
  const int t = threadIdx.x, wv = t >> 6, l = t & 63;
  const int r0 = blockIdx.x * 16;
  __shared__ float buf[4][16][32];
  __shared__ float bsq[4][16];
  __shared__ float gm[16][20];   // [batch][0..15]=M, [16..19]=H_pre

  f32x4 acc[2] = {};
  float sq = 0.f;
  const int kbase = wv * 768;
  const size_t arow = (size_t)(r0 + (l & 15)) * 3072;
  const int koff = (l >> 4) * 8;
#pragma unroll 1
  for (int ks = 0; ks < 24; ++ks) {
    const int k0 = kbase + ks * 32 + koff;
    const f32x4 a0 = *(const f32x4*)(x + arow + k0);
    const f32x4 a1 = *(const f32x4*)(x + arow + k0 + 4);
    sq += a0[0]*a0[0] + a0[1]*a0[1] + a0[2]*a0[2] + a0[3]*a0[3]
        + a1[0]*a1[0] + a1[1]*a1[1] + a1[2]*a1[2] + a1[3]*a1[3];
    bf16x8 af;
#pragma unroll
    for (int e = 0; e < 4; ++e) { af[e] = (bf16)a0[e]; af[4 + e] = (bf16)a1[e]; }
#pragma unroll
    for (int nf = 0; nf < 2; ++nf) {
      const bf16x8 bn = *(const bf16x8*)(wnb + (size_t)(nf * 16 + (l & 15)) * 3072 + k0);
      acc[nf] = __builtin_amdgcn_mfma_f32_16x16x32_bf16(af, bn, acc[nf], 0, 0, 0);
    }
  }
  sq += __shfl_xor(sq, 16);
  sq += __shfl_xor(sq, 32);
#pragma unroll
  for (int nf = 0; nf < 2; ++nf)
#pragma unroll
    for (int j = 0; j < 4; ++j)
      buf[wv][(l >> 4) * 4 + j][nf * 16 + (l & 15)] = acc[nf][j];
  if (l < 16) bsq[wv][l] = sq;
  __syncthreads();

  if (t < 16) {
    const int r = t;
    float dv[24];
#pragma unroll
    for (int j = 0; j < 24; ++j)
      dv[j] = buf[0][r][j] + buf[1][r][j] + buf[2][r][j] + buf[3][r][j];
    const float ssq = bsq[0][r] + bsq[1][r] + bsq[2][r] + bsq[3][r];
    const float rms = rsqrtf(ssq * (1.f / 3072.f) + EPS_RMS);
    const float ap = alpha_pre[0], apo = alpha_post[0], ar = alpha_res[0];
    float* g = gates + (size_t)(r0 + r) * 24;
    float M[16];
    float hp[4];
#pragma unroll
    for (int j = 0; j < 4; ++j) {
      const float p = ap * rms * dv[j] + b_pre[j];
      hp[j] = 1.f / (1.f + __expf(-p));
      g[j] = hp[j];
      const float q = apo * rms * dv[4 + j] + b_post[j];
      g[4 + j] = 2.f / (1.f + __expf(-q));
    }
#pragma unroll
    for (int j = 0; j < 16; ++j) M[j] = __expf(ar * rms * dv[8 + j] + b_res[j]);
    for (int it = 0; it < 20; ++it) {
#pragma unroll
      for (int i = 0; i < 4; ++i) {
        const float s = M[i * 4] + M[i * 4 + 1] + M[i * 4 + 2] + M[i * 4 + 3] + EPS_SK;
        const float ri = __fdividef(1.f, s);
#pragma unroll
        for (int j = 0; j < 4; ++j) M[i * 4 + j] *= ri;
      }
#pragma unroll
      for (int j = 0; j < 4; ++j) {
        const float s = M[j] + M[4 + j] + M[8 + j] + M[12 + j] + EPS_SK;
        const float ri = __fdividef(1.f, s);
#pragma unroll
        for (int i = 0; i < 4; ++i) M[i * 4 + j] *= ri;
      }
    }
#pragma unroll
    for (int j = 0; j < 16; ++j) { g[8 + j] = M[j]; gm[r][j] = M[j]; }
#pragma unroll
    for (int j = 0; j < 4; ++j) gm[r][16 + j] = hp[j];
  }
  __syncthreads();

  // ---- fused mix: 16 threads per batch, 12 f32x4 column-chunks each ----
  const int bb = t >> 4, tt = t & 15;
  float mr[4][4], mp[4][4];
#pragma unroll
  for (int i = 0; i < 4; ++i)
#pragma unroll
    for (int j = 0; j < 4; ++j) {
      mr[i][j] = gm[bb][i * 4 + j];
      mp[i][j] = mr[i][j] * gm[bb][16 + j];
    }
  const size_t xb = (size_t)(r0 + bb) * 3072;
#pragma unroll 1
  for (int cc = 0; cc < 12; ++cc) {
    const int c4 = (tt + cc * 16) * 4;
    f32x4 xj[4];
#pragma unroll
    for (int j = 0; j < 4; ++j)
      xj[j] = *(const f32x4*)(x + xb + (size_t)j * 768 + c4);
#pragma unroll
    for (int i = 0; i < 4; ++i) {
      f32x4 vr = mr[i][0] * xj[0] + mr[i][1] * xj[1] + mr[i][2] * xj[2] + mr[i][3] * xj[3];
      f32x4 vs = mp[i][0] * xj[0] + mp[i][1] * xj[1] + mp[i][2] * xj[2] + mp[i][3] * xj[3];
      bf16x4 ro, so;
#pragma unroll
      for (int q = 0; q < 4; ++q) { ro[q] = (bf16)vr[q]; so[q] = (bf16)vs[q]; }
      *(bf16x4*)(resb + xb + (size_t)i * 768 + c4) = ro;
      *(bf16x4*)(xs   + xb + (size_t)i * 768 + c4) = so;
    }
  }
}

// =============== m97-style 128x128 4-wave GEMM core (R5 structure, 16x16x32) ===============
// R8 change vs R5: the 8 staging source pointers are hoisted out of the K-loop and
// advanced by 64 elems (128 B) per iteration — removes the per-K-step 64-bit address
// recompute (~75 VALU/K-step, the co-limiter in ffn1 per R5's 53% VALUBusy).
// Dst LDS slots are loop-constant. Staging layout identical to R5 (verified).
__device__ __forceinline__ void gemm128_core(
    const bf16* __restrict__ A, const bf16* __restrict__ B, const int K,
    const int tM, const int tN, char* AL, char* BL, f32x4 (&acc)[4][4]) {
  const int t = threadIdx.x, l = t & 63, w = t >> 6;
  const int wr = w >> 1, wc = w & 1;
  const int NT = K >> 6;
  const int arow = wr * 64 + (l & 15);
  const int brow = wc * 64 + (l & 15);
  const int cb = l >> 4;

  auto frag = [&](const char* base, int row, int ks) -> bf16x8 {
    const int c = ks * 4 + cb;
    return *(const bf16x8*)(base + row * 128 + ((c ^ (row & 7)) << 4));
  };

  // hoisted staging addresses: row r0 = t>>3 (0..31), source granule c0s (XOR-swizzled)
  const int r0 = t >> 3;
  const int c0s = (t & 7) ^ (r0 & 7);
  const bf16* as0 = A + (size_t)(tM +      r0) * K + c0s * 8;   // A blk0, rows 0-31
  const bf16* as1 = A + (size_t)(tM + 32 + r0) * K + c0s * 8;   // A blk0, rows 32-63
  const bf16* as2 = A + (size_t)(tM + 64 + r0) * K + c0s * 8;   // A blk1, rows 64-95
  const bf16* as3 = A + (size_t)(tM + 96 + r0) * K + c0s * 8;   // A blk1, rows 96-127
  const bf16* bs0 = B + (size_t)(tN +      r0) * K + c0s * 8;
  const bf16* bs1 = B + (size_t)(tN + 32 + r0) * K + c0s * 8;
  const bf16* bs2 = B + (size_t)(tN + 64 + r0) * K + c0s * 8;
  const bf16* bs3 = B + (size_t)(tN + 96 + r0) * K + c0s * 8;
  char* ad0 = AL + t * 16;                 // blk0, lane t
  char* ad1 = AL + t * 16 + 4096;          // blk0, lane t+256
  char* ad2 = AL + 8192 + t * 16;          // blk1, lane t
  char* ad3 = AL + 8192 + t * 16 + 4096;   // blk1, lane t+256
  char* bd0 = BL + t * 16;
  char* bd1 = BL + t * 16 + 4096;
  char* bd2 = BL + 8192 + t * 16;
  char* bd3 = BL + 8192 + t * 16 + 4096;

#pragma unroll 1
  for (int T = 0; T < NT; ++T) {
    async_copy16(ad0, as0); async_copy16(ad1, as1);
    async_copy16(bd0, bs0); async_copy16(bd1, bs1);
    async_copy16(ad2, as2); async_copy16(ad3, as3);
    async_copy16(bd2, bs2); async_copy16(bd3, bs3);
    as0 += 64; as1 += 64; as2 += 64; as3 += 64;
    bs0 += 64; bs1 += 64; bs2 += 64; bs3 += 64;
    wait_vmcnt0();
    __builtin_amdgcn_s_barrier();
#pragma unroll
    for (int ks = 0; ks < 2; ++ks) {
      bf16x8 af[4], bv[4];
#pragma unroll
      for (int mi = 0; mi < 4; ++mi) af[mi] = frag(AL, arow + mi * 16, ks);
#pragma unroll
      for (int ni = 0; ni < 4; ++ni) bv[ni] = frag(BL, brow + ni * 16, ks);
#pragma unroll
      for (int mi = 0; mi < 4; ++mi)
#pragma unroll
        for (int ni = 0; ni < 4; ++ni)
          acc[mi][ni] = __builtin_amdgcn_mfma_f32_16x16x32_bf16(af[mi], bv[ni], acc[mi][ni], 0, 0, 0);
    }
    __builtin_amdgcn_s_barrier();
  }
}

// ---------------- K3: h = gelu(xs @ w1^T + b1). BM=128, BN=128 ----------------
__global__ __launch_bounds__(256, 3) void ffn1_kernel(
    const bf16* __restrict__ xs, const bf16* __restrict__ w1b,
    const float* __restrict__ b1, bf16* __restrict__ h) {
  __shared__ __align__(16) char LDS[32768];
  int bx, by; xcd_swizzle(bx, by);
  const int tM = by * 128, tN = bx * 128;
  f32x4 acc[4][4] = {};
  gemm128_core(xs, w1b, 768, tM, tN, LDS, LDS + 16384, acc);

  const int t = threadIdx.x, l = t & 63;
  const int w = t >> 6, wr = w >> 1, wc = w & 1;
  float bias[4];
#pragma unroll
  for (int ni = 0; ni < 4; ++ni) bias[ni] = b1[tN + wc * 64 + ni * 16 + (l & 15)];

  __syncthreads();                        // K-loop done; LDS reusable
  float* wlds = (float*)(LDS + w * 8192); // per-wave 16 rows x 64 cols f32, stride 68
#pragma unroll
  for (int mi = 0; mi < 4; ++mi) {
#pragma unroll
    for (int j = 0; j < 4; ++j) {
      const int r = (l >> 4) * 4 + j;
#pragma unroll
      for (int ni = 0; ni < 4; ++ni) {
        const float v = acc[mi][ni][j] + bias[ni];
        const float y2 = 1.5957691216f * (v + 0.044715f * v * v * v);
        wlds[r * 68 + ni * 16 + (l & 15)] = __fdividef(v, 1.f + __expf(-y2));
      }
    }
    const int rr = l >> 3, c0 = (l & 7) * 8;
#pragma unroll
    for (int half = 0; half < 2; ++half) {
      const int row = rr + half * 8;
      const f32x4 u0 = *(const f32x4*)(wlds + row * 68 + c0);
      const f32x4 u1 = *(const f32x4*)(wlds + row * 68 + c0 + 4);
      bf16x8 ov;
#pragma unroll
      for (int q = 0; q < 4; ++q) { ov[q] = (bf16)u0[q]; ov[4 + q] = (bf16)u1[q]; }
      *(bf16x8*)(h + (size_t)(tM + wr * 64 + mi * 16 + row) * 3072 + tN + wc * 64 + c0) = ov;
    }
  }
}

// ---------------- K4: out = res_bf16 + (h @ w2^T + b2) * H_post. BM=128, BN=128 ----------------
__global__ __launch_bounds__(256, 3) void ffn2_kernel(
    const bf16* __restrict__ h, const bf16* __restrict__ w2b,
    const float* __restrict__ b2, const float* __restrict__ gates,
    const bf16* __restrict__ resb, float* __restrict__ outp, const int m0) {
  __shared__ __align__(16) char LDS[32768];
  int bx, by; xcd_swizzle(bx, by);
  const int tM = by * 128, tN = bx * 128;
  f32x4 acc[4][4] = {};
  gemm128_core(h, w2b, 3072, tM, tN, LDS, LDS + 16384, acc);

  const int t = threadIdx.x, l = t & 63;
  const int w = t >> 6, wr = w >> 1, wc = w & 1;
  float bias[4];
#pragma unroll
  for (int ni = 0; ni < 4; ++ni) bias[ni] = b2[tN + wc * 64 + ni * 16 + (l & 15)];

  __syncthreads();                        // K-loop done; LDS reusable
  float* wlds = (float*)(LDS + w * 8192); // per-wave 16 rows x 64 cols f32, stride 68
#pragma unroll
  for (int mi = 0; mi < 4; ++mi) {
#pragma unroll
    for (int j = 0; j < 4; ++j) {
      const int r = (l >> 4) * 4 + j;
#pragma unroll
      for (int ni = 0; ni < 4; ++ni)
        wlds[r * 68 + ni * 16 + (l & 15)] = acc[mi][ni][j] + bias[ni];
    }
#pragma unroll
    for (int rep = 0; rep < 4; ++rep) {
      const int row = rep * 4 + (l >> 4);   // 0..15
      const int cs = l & 15;                // f32x4 chunk within 64 cols
      const int mG = m0 + tM + wr * 64 + mi * 16 + row;
      const float hp = gates[(size_t)(mG >> 2) * 24 + 4 + (mG & 3)];
      const f32x4 v = *(const f32x4*)(wlds + row * 68 + cs * 4);
      const bf16x4 rb = *(const bf16x4*)(resb + (size_t)mG * 768 + tN + wc * 64 + cs * 4);
      f32x4 o;
#pragma unroll
      for (int q = 0; q < 4; ++q) o[q] = (float)rb[q] + v[q] * hp;
      *(f32x4*)(outp + (size_t)mG * 768 + tN + wc * 64 + cs * 4) = o;
    }
  }
}

// ---------------- launcher ----------------
extern "C" void kernel_launch(void* const* d_in, const int* in_sizes, int n_in,
                              void* d_out, int out_size, void* d_ws, size_t ws_size,
                              hipStream_t stream) {
  (void)in_sizes; (void)n_in; (void)out_size;
  const float* x         = (const float*)d_in[0];
  const float* norm_w    = (const float*)d_in[1];
  const float* w_pre     = (const float*)d_in[2];
  const float* b_pre     = (const float*)d_in[3];
  const float* w_post    = (const float*)d_in[4];
  const float* b_post    = (const float*)d_in[5];
  const float* w_res     = (const float*)d_in[6];
  const float* b_res     = (const float*)d_in[7];
  const float* alpha_pre = (const float*)d_in[8];
  const float* alpha_post= (const float*)d_in[9];
  const float* alpha_res = (const float*)d_in[10];
  const float* w1        = (const float*)d_in[11];
  const float* b1        = (const float*)d_in[12];
  const float* w2        = (const float*)d_in[13];
  const float* b2        = (const float*)d_in[14];
  float* outp = (float*)d_out;

  char* ws = (char*)d_ws;
  float* gates = (float*)ws;                        //   786432 B
  bf16*  w1b   = (bf16*)(ws + 786432);              //  4718592 B
  bf16*  w2b   = (bf16*)(ws + 5505024);             //  4718592 B
  bf16*  xs    = (bf16*)(ws + 10223616);            // 50331648 B
  bf16*  resb  = (bf16*)(ws + 60555264);            // 50331648 B
  bf16*  wnb   = (bf16*)(ws + 110886912);           //   196608 B
  bf16*  h     = (bf16*)(ws + 111083520);           // chunked

  size_t avail = ws_size > 111083520 ? ws_size - 111083520 : 0;
  long hrows = (long)(avail / (3072 * 2));
  hrows = (hrows / 256) * 256;
  if (hrows > 32768) hrows = 32768;
  if (hrows < 256) hrows = 256;

  convert_w_kernel<<<dim3(2304), dim3(256), 0, stream>>>(w1, w2, w1b, w2b);
  prep_wnb_kernel<<<dim3(96), dim3(256), 0, stream>>>(w_pre, w_post, w_res, norm_w, wnb);
  gates_kernel<<<dim3(512), dim3(256), 0, stream>>>(
      x, wnb, b_pre, b_post, b_res, alpha_pre, alpha_post, alpha_res, gates, xs, resb);

  for (long mo = 0; mo < 32768; mo += hrows) {
    const long mm = (32768 - mo) < hrows ? (32768 - mo) : hrows;
    ffn1_kernel<<<dim3(24, (unsigned)(mm / 128)), dim3(256), 0, stream>>>(
        xs + mo * 768, w1b, b1, h);
    ffn2_kernel<<<dim3(6, (unsigned)(mm / 128)), dim3(256), 0, stream>>>(
        h, w2b, b2, gates, resb, outp, (int)mo);
  }
}

// Round 9
// 441.972 us; speedup vs baseline: 1.6332x; 1.0039x over previous
//
#include <hip/hip_runtime.h>

#define EPS_RMS 1.1920929e-7f
#define EPS_SK  1e-6f

typedef __bf16 bf16;
typedef __bf16 bf16x4 __attribute__((ext_vector_type(4)));
typedef __bf16 bf16x8 __attribute__((ext_vector_type(8)));
typedef float  f32x4  __attribute__((ext_vector_type(4)));

typedef __attribute__((address_space(3))) void lds_void;
typedef __attribute__((address_space(1))) void glb_void;

__device__ __forceinline__ void async_copy16(void* lds_dst, const void* gsrc) {
  __builtin_amdgcn_global_load_lds((glb_void*)gsrc, (lds_void*)lds_dst, 16, 0, 0);
}

__device__ __forceinline__ void wait_vmcnt0() {
  asm volatile("s_waitcnt vmcnt(0)" ::: "memory");
}

// bijective XCD-chunk swizzle (m204)
__device__ __forceinline__ void xcd_swizzle(int& bx, int& by) {
  const int gx = gridDim.x, nwg = gx * gridDim.y;
  const int flat = blockIdx.y * gx + blockIdx.x;
  const int q = nwg >> 3, r = nwg & 7;
  const int xcd = flat & 7, i = flat >> 3;
  const int lin = (xcd < r ? xcd * (q + 1) : r * (q + 1) + (xcd - r) * q) + i;
  bx = lin % gx;
  by = lin / gx;
}

// ---------------- K0a: convert w1, w2 to bf16 ----------------
__global__ __launch_bounds__(256) void convert_w_kernel(
    const float* __restrict__ w1, const float* __restrict__ w2,
    bf16* __restrict__ w1b, bf16* __restrict__ w2b) {
  size_t i = ((size_t)blockIdx.x * 256 + threadIdx.x) * 4;
  f32x4 a = *(const f32x4*)(w1 + i);
  f32x4 b = *(const f32x4*)(w2 + i);
  bf16x4 ab, bb;
#pragma unroll
  for (int q = 0; q < 4; ++q) { ab[q] = (bf16)a[q]; bb[q] = (bf16)b[q]; }
  *(bf16x4*)(w1b + i) = ab;
  *(bf16x4*)(w2b + i) = bb;
}

// ---------------- K0b: wnb[32][3072] bf16 = cat(w_pre,w_post,w_res,0)*norm_w ----------------
__global__ __launch_bounds__(256) void prep_wnb_kernel(
    const float* __restrict__ w_pre, const float* __restrict__ w_post,
    const float* __restrict__ w_res, const float* __restrict__ norm_w,
    bf16* __restrict__ wnb) {
  const int i = (blockIdx.x * 256 + threadIdx.x) * 4;   // 98304 total elems
  const int j = i / 3072, k = i - j * 3072;
  f32x4 wv;
  if (j < 24) {
    const float* src = j < 4 ? (w_pre + j * 3072)
                     : (j < 8 ? (w_post + (j - 4) * 3072) : (w_res + (j - 8) * 3072));
    const f32x4 nv = *(const f32x4*)(norm_w + k);
    wv = *(const f32x4*)(src + k);
    wv = wv * nv;
  } else {
    wv = f32x4{0.f, 0.f, 0.f, 0.f};
  }
  bf16x4 o;
#pragma unroll
  for (int q = 0; q < 4; ++q) o[q] = (bf16)wv[q];
  *(bf16x4*)(wnb + i) = o;
}

// ---------------- K1: gate logits via MFMA + fused stream-mix ----------------
__global__ __launch_bounds__(256) void gates_kernel(
    const float* __restrict__ x, const bf16* __restrict__ wnb,
    const float* __restrict__ b_pre, const float* __restrict__ b_post,
    const float* __restrict__ b_res,
    const float* __restrict__ alpha_pre, const float* __restrict__ alpha_post,
    const float* __restrict__ alpha_res, float* __restrict__ gates,
    bf16* __restrict__ xs, bf16* __restrict__ resb) {
  const int t = threadIdx.x, wv = t >> 6, l = t & 63;
  const int r0 = blockIdx.x * 16;
  __shared__ float buf[4][16][32];
  __shared__ float bsq[4][16];
  __shared__ float gm[16][20];   // [batch][0..15]=M, [16..19]=H_pre

  f32x4 acc[2] = {};
  float sq = 0.f;
  const int kbase = wv * 768;
  const size_t arow = (size_t)(r0 + (l & 15)) * 3072;
  const int koff = (l >> 4) * 8;
#pragma unroll 1
  for (int ks = 0; ks < 24; ++ks) {
    const int k0 = kbase + ks * 32 + koff;
    const f32x4 a0 = *(const f32x4*)(x + arow + k0);
    const f32x4 a1 = *(const f32x4*)(x + arow + k0 + 4);
    sq += a0[0]*a0[0] + a0[1]*a0[1] + a0[2]*a0[2] + a0[3]*a0[3]
        + a1[0]*a1[0] + a1[1]*a1[1] + a1[2]*a1[2] + a1[3]*a1[3];
    bf16x8 af;
#pragma unroll
    for (int e = 0; e < 4; ++e) { af[e] = (bf16)a0[e]; af[4 + e] = (bf16)a1[e]; }
#pragma unroll
    for (int nf = 0; nf < 2; ++nf) {
      const bf16x8 bn = *(const bf16x8*)(wnb + (size_t)(nf * 16 + (l & 15)) * 3072 + k0);
      acc[nf] = __builtin_amdgcn_mfma_f32_16x16x32_bf16(af, bn, acc[nf], 0, 0, 0);
    }
  }
  sq += __shfl_xor(sq, 16);
  sq += __shfl_xor(sq, 32);
#pragma unroll
  for (int nf = 0; nf < 2; ++nf)
#pragma unroll
    for (int j = 0; j < 4; ++j)
      buf[wv][(l >> 4) * 4 + j][nf * 16 + (l & 15)] = acc[nf][j];
  if (l < 16) bsq[wv][l] = sq;
  __syncthreads();

  if (t < 16) {
    const int r = t;
    float dv[24];
#pragma unroll
    for (int j = 0; j < 24; ++j)
      dv[j] = buf[0][r][j] + buf[1][r][j] + buf[2][r][j] + buf[3][r][j];
    const float ssq = bsq[0][r] + bsq[1][r] + bsq[2][r] + bsq[3][r];
    const float rms = rsqrtf(ssq * (1.f / 3072.f) + EPS_RMS);
    const float ap = alpha_pre[0], apo = alpha_post[0], ar = alpha_res[0];
    float* g = gates + (size_t)(r0 + r) * 24;
    float M[16];
    float hp[4];
#pragma unroll
    for (int j = 0; j < 4; ++j) {
      const float p = ap * rms * dv[j] + b_pre[j];
      hp[j] = 1.f / (1.f + __expf(-p));
      g[j] = hp[j];
      const float q = apo * rms * dv[4 + j] + b_post[j];
      g[4 + j] = 2.f / (1.f + __expf(-q));
    }
#pragma unroll
    for (int j = 0; j < 16; ++j) M[j] = __expf(ar * rms * dv[8 + j] + b_res[j]);
    for (int it = 0; it < 20; ++it) {
#pragma unroll
      for (int i = 0; i < 4; ++i) {
        const float s = M[i * 4] + M[i * 4 + 1] + M[i * 4 + 2] + M[i * 4 + 3] + EPS_SK;
        const float ri = __fdividef(1.f, s);
#pragma unroll
        for (int j = 0; j < 4; ++j) M[i * 4 + j] *= ri;
      }
#pragma unroll
      for (int j = 0; j < 4; ++j) {
        const float s = M[j] + M[4 + j] + M[8 + j] + M[12 + j] + EPS_SK;
        const float ri = __fdividef(1.f, s);
#pragma unroll
        for (int i = 0; i < 4; ++i) M[i * 4 + j] *= ri;
      }
    }
#pragma unroll
    for (int j = 0; j < 16; ++j) { g[8 + j] = M[j]; gm[r][j] = M[j]; }
#pragma unroll
    for (int j = 0; j < 4; ++j) gm[r][16 + j] = hp[j];
  }
  __syncthreads();

  // ---- fused mix: 16 threads per batch, 12 f32x4 column-chunks each ----
  const int bb = t >> 4, tt = t & 15;
  float mr[4][4], mp[4][4];
#pragma unroll
  for (int i = 0; i < 4; ++i)
#pragma unroll
    for (int j = 0; j < 4; ++j) {
      mr[i][j] = gm[bb][i * 4 + j];
      mp[i][j] = mr[i][j] * gm[bb][16 + j];
    }
  const size_t xb = (size_t)(r0 + bb) * 3072;
#pragma unroll 1
  for (int cc = 0; cc < 12; ++cc) {
    const int c4 = (tt + cc * 16) * 4;
    f32x4 xj[4];
#pragma unroll
    for (int j = 0; j < 4; ++j)
      xj[j] = *(const f32x4*)(x + xb + (size_t)j * 768 + c4);
#pragma unroll
    for (int i = 0; i < 4; ++i) {
      f32x4 vr = mr[i][0] * xj[0] + mr[i][1] * xj[1] + mr[i][2] * xj[2] + mr[i][3] * xj[3];
      f32x4 vs = mp[i][0] * xj[0] + mp[i][1] * xj[1] + mp[i][2] * xj[2] + mp[i][3] * xj[3];
      bf16x4 ro, so;
#pragma unroll
      for (int q = 0; q < 4; ++q) { ro[q] = (bf16)vr[q]; so[q] = (bf16)vs[q]; }
      *(bf16x4*)(resb + xb + (size_t)i * 768 + c4) = ro;
      *(bf16x4*)(xs   + xb + (size_t)i * 768 + c4) = so;
    }
  }
}

// =============== m97-style 128x128 4-wave GEMM core (R5/R8 structure, 16x16x32) ===============
__device__ __forceinline__ void gemm128_core(
    const bf16* __restrict__ A, const bf16* __restrict__ B, const int K,
    const int tM, const int tN, char* AL, char* BL, f32x4 (&acc)[4][4]) {
  const int t = threadIdx.x, l = t & 63, w = t >> 6;
  const int wr = w >> 1, wc = w & 1;
  const int NT = K >> 6;
  const int arow = wr * 64 + (l & 15);
  const int brow = wc * 64 + (l & 15);
  const int cb = l >> 4;

  auto frag = [&](const char* base, int row, int ks) -> bf16x8 {
    const int c = ks * 4 + cb;
    return *(const bf16x8*)(base + row * 128 + ((c ^ (row & 7)) << 4));
  };

  // hoisted staging addresses: row r0 = t>>3 (0..31), source granule c0s (XOR-swizzled)
  const int r0 = t >> 3;
  const int c0s = (t & 7) ^ (r0 & 7);
  const bf16* as0 = A + (size_t)(tM +      r0) * K + c0s * 8;   // A blk0, rows 0-31
  const bf16* as1 = A + (size_t)(tM + 32 + r0) * K + c0s * 8;   // A blk0, rows 32-63
  const bf16* as2 = A + (size_t)(tM + 64 + r0) * K + c0s * 8;   // A blk1, rows 64-95
  const bf16* as3 = A + (size_t)(tM + 96 + r0) * K + c0s * 8;   // A blk1, rows 96-127
  const bf16* bs0 = B + (size_t)(tN +      r0) * K + c0s * 8;
  const bf16* bs1 = B + (size_t)(tN + 32 + r0) * K + c0s * 8;
  const bf16* bs2 = B + (size_t)(tN + 64 + r0) * K + c0s * 8;
  const bf16* bs3 = B + (size_t)(tN + 96 + r0) * K + c0s * 8;
  char* ad0 = AL + t * 16;                 // blk0, lane t
  char* ad1 = AL + t * 16 + 4096;          // blk0, lane t+256
  char* ad2 = AL + 8192 + t * 16;          // blk1, lane t
  char* ad3 = AL + 8192 + t * 16 + 4096;   // blk1, lane t+256
  char* bd0 = BL + t * 16;
  char* bd1 = BL + t * 16 + 4096;
  char* bd2 = BL + 8192 + t * 16;
  char* bd3 = BL + 8192 + t * 16 + 4096;

#pragma unroll 1
  for (int T = 0; T < NT; ++T) {
    async_copy16(ad0, as0); async_copy16(ad1, as1);
    async_copy16(bd0, bs0); async_copy16(bd1, bs1);
    async_copy16(ad2, as2); async_copy16(ad3, as3);
    async_copy16(bd2, bs2); async_copy16(bd3, bs3);
    as0 += 64; as1 += 64; as2 += 64; as3 += 64;
    bs0 += 64; bs1 += 64; bs2 += 64; bs3 += 64;
    wait_vmcnt0();
    __builtin_amdgcn_s_barrier();
#pragma unroll
    for (int ks = 0; ks < 2; ++ks) {
      bf16x8 af[4], bv[4];
#pragma unroll
      for (int mi = 0; mi < 4; ++mi) af[mi] = frag(AL, arow + mi * 16, ks);
#pragma unroll
      for (int ni = 0; ni < 4; ++ni) bv[ni] = frag(BL, brow + ni * 16, ks);
#pragma unroll
      for (int mi = 0; mi < 4; ++mi)
#pragma unroll
        for (int ni = 0; ni < 4; ++ni)
          acc[mi][ni] = __builtin_amdgcn_mfma_f32_16x16x32_bf16(af[mi], bv[ni], acc[mi][ni], 0, 0, 0);
    }
    __builtin_amdgcn_s_barrier();
  }
}

// ---------------- K3: h = gelu(xs @ w1^T + b1). BM=128, BN=128 ----------------
__global__ __launch_bounds__(256, 3) void ffn1_kernel(
    const bf16* __restrict__ xs, const bf16* __restrict__ w1b,
    const float* __restrict__ b1, bf16* __restrict__ h) {
  __shared__ __align__(16) char LDS[32768];
  int bx, by; xcd_swizzle(bx, by);
  const int tM = by * 128, tN = bx * 128;
  f32x4 acc[4][4] = {};
  gemm128_core(xs, w1b, 768, tM, tN, LDS, LDS + 16384, acc);

  const int t = threadIdx.x, l = t & 63;
  const int w = t >> 6, wr = w >> 1, wc = w & 1;
  float bias[4];
#pragma unroll
  for (int ni = 0; ni < 4; ++ni) bias[ni] = b1[tN + wc * 64 + ni * 16 + (l & 15)];

  __syncthreads();                        // K-loop done; LDS reusable
  float* wlds = (float*)(LDS + w * 8192); // per-wave 16 rows x 64 cols f32, stride 68
#pragma unroll
  for (int mi = 0; mi < 4; ++mi) {
#pragma unroll
    for (int j = 0; j < 4; ++j) {
      const int r = (l >> 4) * 4 + j;
#pragma unroll
      for (int ni = 0; ni < 4; ++ni) {
        const float v = acc[mi][ni][j] + bias[ni];
        const float y2 = 1.5957691216f * (v + 0.044715f * v * v * v);
        wlds[r * 68 + ni * 16 + (l & 15)] = __fdividef(v, 1.f + __expf(-y2));
      }
    }
    const int rr = l >> 3, c0 = (l & 7) * 8;
#pragma unroll
    for (int half = 0; half < 2; ++half) {
      const int row = rr + half * 8;
      const f32x4 u0 = *(const f32x4*)(wlds + row * 68 + c0);
      const f32x4 u1 = *(const f32x4*)(wlds + row * 68 + c0 + 4);
      bf16x8 ov;
#pragma unroll
      for (int q = 0; q < 4; ++q) { ov[q] = (bf16)u0[q]; ov[4 + q] = (bf16)u1[q]; }
      *(bf16x8*)(h + (size_t)(tM + wr * 64 + mi * 16 + row) * 3072 + tN + wc * 64 + c0) = ov;
    }
  }
}

// ---------------- K4: out = res_bf16 + (h @ w2^T + b2) * H_post. BM=128, BN=128 ----------------
__global__ __launch_bounds__(256, 3) void ffn2_kernel(
    const bf16* __restrict__ h, const bf16* __restrict__ w2b,
    const float* __restrict__ b2, const float* __restrict__ gates,
    const bf16* __restrict__ resb, float* __restrict__ outp, const int m0) {
  __shared__ __align__(16) char LDS[32768];
  int bx, by; xcd_swizzle(bx, by);
  const int tM = by * 128, tN = bx * 128;
  f32x4 acc[4][4] = {};
  gemm128_core(h, w2b, 3072, tM, tN, LDS, LDS + 16384, acc);

  const int t = threadIdx.x, l = t & 63;
  const int w = t >> 6, wr = w >> 1, wc = w & 1;
  float bias[4];
#pragma unroll
  for (int ni = 0; ni < 4; ++ni) bias[ni] = b2[tN + wc * 64 + ni * 16 + (l & 15)];

  __syncthreads();                        // K-loop done; LDS reusable
  float* wlds = (float*)(LDS + w * 8192); // per-wave 16 rows x 64 cols f32, stride 68
#pragma unroll
  for (int mi = 0; mi < 4; ++mi) {
#pragma unroll
    for (int j = 0; j < 4; ++j) {
      const int r = (l >> 4) * 4 + j;
#pragma unroll
      for (int ni = 0; ni < 4; ++ni)
        wlds[r * 68 + ni * 16 + (l & 15)] = acc[mi][ni][j] + bias[ni];
    }
#pragma unroll
    for (int rep = 0; rep < 4; ++rep) {
      const int row = rep * 4 + (l >> 4);   // 0..15
      const int cs = l & 15;                // f32x4 chunk within 64 cols
      const int mG = m0 + tM + wr * 64 + mi * 16 + row;
      const float hp = gates[(size_t)(mG >> 2) * 24 + 4 + (mG & 3)];
      const f32x4 v = *(const f32x4*)(wlds + row * 68 + cs * 4);
      const bf16x4 rb = *(const bf16x4*)(resb + (size_t)mG * 768 + tN + wc * 64 + cs * 4);
      f32x4 o;
#pragma unroll
      for (int q = 0; q < 4; ++q) o[q] = (float)rb[q] + v[q] * hp;
      *(f32x4*)(outp + (size_t)mG * 768 + tN + wc * 64 + cs * 4) = o;
    }
  }
}

// ---------------- launcher ----------------
extern "C" void kernel_launch(void* const* d_in, const int* in_sizes, int n_in,
                              void* d_out, int out_size, void* d_ws, size_t ws_size,
                              hipStream_t stream) {
  (void)in_sizes; (void)n_in; (void)out_size;
  const float* x         = (const float*)d_in[0];
  const float* norm_w    = (const float*)d_in[1];
  const float* w_pre     = (const float*)d_in[2];
  const float* b_pre     = (const float*)d_in[3];
  const float* w_post    = (const float*)d_in[4];
  const float* b_post    = (const float*)d_in[5];
  const float* w_res     = (const float*)d_in[6];
  const float* b_res     = (const float*)d_in[7];
  const float* alpha_pre = (const float*)d_in[8];
  const float* alpha_post= (const float*)d_in[9];
  const float* alpha_res = (const float*)d_in[10];
  const float* w1        = (const float*)d_in[11];
  const float* b1        = (const float*)d_in[12];
  const float* w2        = (const float*)d_in[13];
  const float* b2        = (const float*)d_in[14];
  float* outp = (float*)d_out;

  char* ws = (char*)d_ws;
  float* gates = (float*)ws;                        //   786432 B
  bf16*  w1b   = (bf16*)(ws + 786432);              //  4718592 B
  bf16*  w2b   = (bf16*)(ws + 5505024);             //  4718592 B
  bf16*  xs    = (bf16*)(ws + 10223616);            // 50331648 B
  bf16*  resb  = (bf16*)(ws + 60555264);            // 50331648 B
  bf16*  wnb   = (bf16*)(ws + 110886912);           //   196608 B
  bf16*  h     = (bf16*)(ws + 111083520);           // chunked

  size_t avail = ws_size > 111083520 ? ws_size - 111083520 : 0;
  long hrows = (long)(avail / (3072 * 2));
  hrows = (hrows / 256) * 256;
  // Cap at 16384 rows: h-chunk = 100 MB -> chunk working set ~200 MB fits the 256 MB
  // L3, so ffn2 reads h from Infinity Cache instead of HBM (staging-latency cut:
  // ~900 cyc HBM-miss vs ~300 L3, m126), and chunk 2 rewrites the same h buffer
  // (halves HBM writeback). Grids stay occupancy-exact: ffn2 = 6x128 = 768 blocks
  // = exactly 3/CU one full round; ffn1 = 24x128 = 4 rounds of 3/CU; both %8==0.
  if (hrows > 16384) hrows = 16384;
  if (hrows < 256) hrows = 256;

  convert_w_kernel<<<dim3(2304), dim3(256), 0, stream>>>(w1, w2, w1b, w2b);
  prep_wnb_kernel<<<dim3(96), dim3(256), 0, stream>>>(w_pre, w_post, w_res, norm_w, wnb);
  gates_kernel<<<dim3(512), dim3(256), 0, stream>>>(
      x, wnb, b_pre, b_post, b_res, alpha_pre, alpha_post, alpha_res, gates, xs, resb);

  for (long mo = 0; mo < 32768; mo += hrows) {
    const long mm = (32768 - mo) < hrows ? (32768 - mo) : hrows;
    ffn1_kernel<<<dim3(24, (unsigned)(mm / 128)), dim3(256), 0, stream>>>(
        xs + mo * 768, w1b, b1, h);
    ffn2_kernel<<<dim3(6, (unsigned)(mm / 128)), dim3(256), 0, stream>>>(
        h, w2b, b2, gates, resb, outp, (int)mo);
  }
}